// Round 6
// baseline (206.576 us; speedup 1.0000x reference)
//
#include <hip/hip_runtime.h>

#define SQL  1024
#define EDIM 256
#define NHD  8
#define NKV  (NHD * 3 * EDIM)   // 6144
#define MROWS (4 * SQL)         // 4096

typedef short bf16x8 __attribute__((ext_vector_type(8)));
typedef short bf16x4 __attribute__((ext_vector_type(4)));
typedef float f32x4 __attribute__((ext_vector_type(4)));

// ---- 16x16x16 bf16 MFMA builtin resolution (guarded; fallback = zero-padded 16x16x32)
#if defined(__has_builtin)
#if __has_builtin(__builtin_amdgcn_mfma_f32_16x16x16bf16_1k)
#define MFMA16(a, b, c) __builtin_amdgcn_mfma_f32_16x16x16bf16_1k(a, b, c, 0, 0, 0)
#define HAVE_MFMA16 1
#elif __has_builtin(__builtin_amdgcn_mfma_f32_16x16x16_bf16)
#define MFMA16(a, b, c) __builtin_amdgcn_mfma_f32_16x16x16_bf16(a, b, c, 0, 0, 0)
#define HAVE_MFMA16 1
#else
#define HAVE_MFMA16 0
#endif
#else
#define HAVE_MFMA16 0
#endif

// Ps row stride (shorts): 20 (=40B, b64-aligned, bank-optimal) for the
// 16x16x16 path; 24 (=48B, 16B-aligned) for the b128 fallback path.
constexpr int PSTR = HAVE_MFMA16 ? 20 : 24;

__device__ __forceinline__ unsigned short f2bf(float f) {
  unsigned u = __float_as_uint(f);
  u += 0x7fff + ((u >> 16) & 1);   // round-to-nearest-even (finite values)
  return (unsigned short)(u >> 16);
}

// async 16B global->LDS (direct-to-shared DMA; LDS dest must be
// wave-uniform base + lane*16 — all call sites use flat (it*T+tid)*16B)
__device__ __forceinline__ void g2lds16(const void* g, void* l) {
  __builtin_amdgcn_global_load_lds(
      (const __attribute__((address_space(1))) unsigned int*)g,
      (__attribute__((address_space(3))) unsigned int*)l, 16, 0, 0);
}

__device__ __forceinline__ void storev(float* p, float v) { *p = v; }
__device__ __forceinline__ void storev(unsigned short* p, float v) { *p = f2bf(v); }

// =====================================================================
// fused fp32 -> bf16 cast for all three inputs, 8 elems/thread.
// =====================================================================
__global__ __launch_bounds__(256) void cast3_bf16(
    const float* __restrict__ s0, unsigned short* __restrict__ d0, int n0,
    const float* __restrict__ s1, unsigned short* __restrict__ d1, int n1,
    const float* __restrict__ s2, unsigned short* __restrict__ d2, int n2) {
  int i = blockIdx.x * 256 + threadIdx.x;
  const float* s; unsigned short* d;
  if (i < n0) { s = s0; d = d0; }
  else if (i < n0 + n1) { i -= n0; s = s1; d = d1; }
  else { i -= n0 + n1; if (i >= n2) return; s = s2; d = d2; }
  float4 a = ((const float4*)s)[2 * i];
  float4 b = ((const float4*)s)[2 * i + 1];
  union { unsigned short u[8]; ulonglong2 v; } t;
  t.u[0] = f2bf(a.x); t.u[1] = f2bf(a.y); t.u[2] = f2bf(a.z); t.u[3] = f2bf(a.w);
  t.u[4] = f2bf(b.x); t.u[5] = f2bf(b.y); t.u[6] = f2bf(b.z); t.u[7] = f2bf(b.w);
  ((ulonglong2*)d)[i] = t.v;
}

// =====================================================================
// bf16 MFMA NT-GEMM, double-buffered global_load_lds staging.
// (round-0 proven version)
// =====================================================================
template <int BM, int BN, typename OutT>
__global__ __launch_bounds__(256) void gemm_mfma(
    const unsigned short* __restrict__ A, const unsigned short* __restrict__ B,
    const float* __restrict__ bias, OutT* __restrict__ C,
    int M, int N, int K) {
  constexpr int TM = BM / 32, TN = BN / 32;
  __shared__ __align__(16) unsigned short As[2][BM * 32];
  __shared__ __align__(16) unsigned short Bs[2][BN * 32];
  const int tid = threadIdx.x;
  const int wave = tid >> 6, lane = tid & 63;
  const int quad = lane >> 4, l16 = lane & 15;
  const int wm = (wave >> 1) * (BM / 2), wn = (wave & 1) * (BN / 2);
  const int m0 = blockIdx.x * BM, n0 = blockIdx.y * BN;
  const int sw = (l16 >> 1) & 3;

  f32x4 acc[TM][TN];
  #pragma unroll
  for (int i = 0; i < TM; i++)
    #pragma unroll
    for (int j = 0; j < TN; j++) acc[i][j] = {0.f, 0.f, 0.f, 0.f};

  auto stage = [&](int k0, int bb) {
    #pragma unroll
    for (int it = 0; it < BM / 64; it++) {
      int flat = it * 256 + tid;
      int row = flat >> 2;
      int cg = (flat & 3) ^ ((row >> 1) & 3);
      g2lds16(A + (size_t)(m0 + row) * K + k0 + cg * 8, &As[bb][flat * 8]);
    }
    #pragma unroll
    for (int it = 0; it < BN / 64; it++) {
      int flat = it * 256 + tid;
      int row = flat >> 2;
      int cg = (flat & 3) ^ ((row >> 1) & 3);
      g2lds16(B + (size_t)(n0 + row) * K + k0 + cg * 8, &Bs[bb][flat * 8]);
    }
  };

  stage(0, 0);
  __syncthreads();
  for (int k0 = 0; k0 < K; k0 += 32) {
    const int bb = (k0 >> 5) & 1;
    if (k0 + 32 < K) stage(k0 + 32, bb ^ 1);
    bf16x8 af[TM], bf[TN];
    #pragma unroll
    for (int i = 0; i < TM; i++)
      af[i] = *(const bf16x8*)&As[bb][(wm + i * 16 + l16) * 32 + (quad ^ sw) * 8];
    #pragma unroll
    for (int j = 0; j < TN; j++)
      bf[j] = *(const bf16x8*)&Bs[bb][(wn + j * 16 + l16) * 32 + (quad ^ sw) * 8];
    #pragma unroll
    for (int i = 0; i < TM; i++)
      #pragma unroll
      for (int j = 0; j < TN; j++)
        acc[i][j] = __builtin_amdgcn_mfma_f32_16x16x32_bf16(af[i], bf[j], acc[i][j], 0, 0, 0);
    __syncthreads();  // gates buffer reuse + drains this iter's prefetch
  }

  #pragma unroll
  for (int i = 0; i < TM; i++) {
    #pragma unroll
    for (int r = 0; r < 4; r++) {
      int m = m0 + wm + i * 16 + quad * 4 + r;
      #pragma unroll
      for (int j = 0; j < TN; j++) {
        int n = n0 + wn + j * 16 + l16;
        storev(&C[(size_t)m * N + n], acc[i][j][r] + bias[n]);
      }
    }
  }
}

// =====================================================================
// V transpose -> kt-tile-major, k-chunk4-major layout:
// vt[bh][kt][c4][d][i]  (short index = (((bh*32+kt)*8 + c4)*256 + d)*4 + i)
// where element = V[key = kt*32 + c4*4 + i][d]. Staging a kt tile into
// LDS is a flat 16KB copy; the PV b64 read VtB[(c4*256+d)*4] has each
// 16-lane quad-group covering all 32 banks (floor-optimal, no swizzle
// needed). Writes here stay coalesced: 64 consecutive lanes write 64
// consecutive 8B chunks (512B runs).
// =====================================================================
__global__ __launch_bounds__(256) void transpose_v(
    const unsigned short* __restrict__ proj, unsigned short* __restrict__ vt) {
  __shared__ unsigned short T[64][66];
  const int tid = threadIdx.x;
  const int s0 = blockIdx.x * 64, d0 = blockIdx.y * 64, bh = blockIdx.z;
  const int b = bh >> 3, h = bh & 7;
  #pragma unroll
  for (int it = 0; it < 2; it++) {
    int c = it * 256 + tid;
    int sr = c >> 3, d8 = (c & 7) * 8;
    int s = s0 + sr;
    const unsigned short* src = proj + (size_t)(b * SQL + h * 128 + (s >> 3)) * NKV
                                + 2 * 2048 + (s & 7) * 256 + d0 + d8;
    *(ulonglong2*)&T[sr][d8] = *(const ulonglong2*)src;
  }
  __syncthreads();
  #pragma unroll
  for (int it = 0; it < 2; it++) {
    int c = it * 256 + tid;
    int dr = c & 63, sg = c >> 6;          // sg in 0..7 (8 keys each)
    unsigned short tmp[8];
    #pragma unroll
    for (int j = 0; j < 8; j++) tmp[j] = T[sg * 8 + j][dr];
    const int d = d0 + dr;
    const int t = (s0 >> 5) + (sg >> 2);   // kt tile index
    const int c4 = (sg & 3) * 2;           // first k-chunk4 of this 8-key group
    unsigned short* base = vt + (((size_t)(bh * 32 + t) * 8 + c4) * 256 + d) * 4;
    uint2 w0, w1;
    w0.x = (unsigned)tmp[0] | ((unsigned)tmp[1] << 16);
    w0.y = (unsigned)tmp[2] | ((unsigned)tmp[3] << 16);
    w1.x = (unsigned)tmp[4] | ((unsigned)tmp[5] << 16);
    w1.y = (unsigned)tmp[6] | ((unsigned)tmp[7] << 16);
    *(uint2*)base          = w0;           // chunk c4
    *(uint2*)(base + 1024) = w1;           // chunk c4+1 (+256*4 shorts)
  }
}

// =====================================================================
// bf16 MFMA flash attention, round 8 (resubmit — round 5 bench was an
// infra failure, no data): 4 waves/SIMD at 1.0x work.
// R0: 2-3 w/SIMD, 1.0x work -> 47us. R3: 4 w/SIMD, 1.5x -> 53. R4:
// 2 w/SIMD (138KB LDS), 1.0x -> 54. This hits the untried quadrant:
// 8 waves (qs 0..3, kh 0..1), each = HALF an R0 wave: QK over a
// private 16-key half (8 MFMA 16x16x32, no duplication), private
// half-softmax (half the exp2 VALU — R3's big duplicated cost),
// private Ps slice [16][PSTR], PV over the key-half via 16x16x16
// MFMA (K=16 matches exactly, ~half the MFMA cycles; __has_builtin-
// guarded with zero-padded-A 16x16x32 fallback). O is key-partial
// per wave -> one cross-kh O/l sum in the epilogue using dead buffer
// space (R4's proven pattern). One barrier per kt, full wave
// independence between barriers (R1 lesson), kt=32 dbuf staging.
// LDS: 2x(K 16KB + V 16KB) + Ps 5KB = 71KB -> 2 blocks/CU x 8 waves
// = 4 waves/SIMD.  V reads are b64 from the tile-major vt layout
// (bank-floor-optimal).
// =====================================================================
__global__ __launch_bounds__(512, 4) void attn_mfma(
    const unsigned short* __restrict__ proj,
    const unsigned short* __restrict__ vt,
    unsigned short* __restrict__ oflat) {
  // shorts: buf0 @0 (K 8192 | V 8192) | buf1 @16384 | Ps @32768 (8 x 16 x PSTR)
  __shared__ __align__(16) unsigned short lds[32768 + 8 * 16 * PSTR];
  __shared__ float lsumX[4][16];
  unsigned short* Ps = lds + 32768;

  const int tid = threadIdx.x;          // 0..511
  const int wave = tid >> 6, lane = tid & 63;
  const int quad = lane >> 4, l16 = lane & 15;
  const int qs = wave >> 1;             // q-row subtile: rows qs*16..+15
  const int kh = wave & 1;              // key half within each kt tile
  // balanced decode: slot s -> (bh = s&31, j = s>>5); round 0 heavy, 1 light
  const int slot = blockIdx.x & 255, round = blockIdx.x >> 8;
  const int bh = slot & 31;
  const int jj = slot >> 5;
  const int qt = round ? jj : 15 - jj;
  const int b = bh >> 3, h = bh & 7;
  const int q0 = qt * 64;

  auto stage = [&](int kt, int bb) {
    unsigned short* B = lds + bb * 16384;
    #pragma unroll
    for (int it = 0; it < 2; it++) {   // K tile 32 x 256 (16KB), swizzled
      int c = it * 512 + tid;
      int r = c >> 5, ch = (c & 31) ^ (r & 7);
      int s = kt * 32 + r;
      g2lds16(proj + (size_t)(b * SQL + h * 128 + (s >> 3)) * NKV + 2048 + (s & 7) * 256 + ch * 8,
              B + c * 8);
    }
    const unsigned short* vsrc = vt + ((size_t)bh * 32 + kt) * 8192;
    #pragma unroll
    for (int it = 0; it < 2; it++) {   // V tile: flat 16KB copy (tile-major layout)
      int c = it * 512 + tid;
      g2lds16(vsrc + c * 8, B + 8192 + c * 8);
    }
  };

  // ---- prologue: kt0 -> buf0, Q (64x256, 32KB) -> buf1 region ----
  stage(0, 0);
  #pragma unroll
  for (int it = 0; it < 4; it++) {
    int c = it * 512 + tid;
    int r = c >> 5, ch = (c & 31) ^ (r & 7);
    int s = q0 + r;
    g2lds16(proj + (size_t)(b * SQL + h * 128 + (s >> 3)) * NKV + (s & 7) * 256 + ch * 8,
            lds + 16384 + c * 8);
  }
  __syncthreads();
  bf16x8 aq[8];
  const int qrow = qs * 16 + l16;
  #pragma unroll
  for (int kk = 0; kk < 8; kk++)
    aq[kk] = *(const bf16x8*)&lds[16384 + qrow * 256 + ((kk * 4 + quad) ^ (qrow & 7)) * 8];
  __syncthreads();  // all waves done reading Q before buf1 overwrite

  f32x4 o[16];
  #pragma unroll
  for (int t = 0; t < 16; t++) o[t] = {0.f, 0.f, 0.f, 0.f};
  float l_r[4] = {0.f, 0.f, 0.f, 0.f};

  const int nkt = 2 * qt + 2;
  for (int kt = 0; kt < nkt; kt++) {
    const int bb = kt & 1;
    if (kt + 1 < nkt) stage(kt + 1, bb ^ 1);  // prefetch into other buffer
    const unsigned short* KsB = lds + bb * 16384;
    const unsigned short* VtB = KsB + 8192;
    // wave's 16 keys: kt*32 + kh*16 .. +15; skip if fully masked
    const bool live = (kt * 32 + kh * 16 <= q0 + qs * 16 + 15);

    if (live) {
      // ---- S = Q K^T : 16 q-rows x my 16-key half (8 MFMA) ----
      f32x4 s0 = {0.f, 0.f, 0.f, 0.f};
      const int krow = kh * 16 + l16;
      #pragma unroll
      for (int kk = 0; kk < 8; kk++) {
        bf16x8 bk = *(const bf16x8*)&KsB[krow * 256 + ((kk * 4 + quad) ^ (l16 & 7)) * 8];
        s0 = __builtin_amdgcn_mfma_f32_16x16x32_bf16(aq[kk], bk, s0, 0, 0, 0);
      }

      // ---- half-softmax: p = exp2(s/16*log2e), lane-local l ----
      const int kg = kt * 32 + kh * 16 + l16;
      unsigned short* PsW = Ps + wave * 16 * PSTR;  // private [16][PSTR]
      #pragma unroll
      for (int r = 0; r < 4; r++) {
        int qg = q0 + qs * 16 + quad * 4 + r;
        float p0 = (kg <= qg) ? exp2f(s0[r] * 0.09016844f) : 0.f;
        l_r[r] += p0;
        PsW[(quad * 4 + r) * PSTR + l16] = f2bf(p0);
      }

      // ---- PV over my 16-key half, full d=256 ----
#if HAVE_MFMA16
      bf16x4 ap = *(const bf16x4*)&PsW[l16 * PSTR + quad * 4];
      #pragma unroll
      for (int tl = 0; tl < 16; tl++) {
        const int d = tl * 16 + l16;
        bf16x4 bv = *(const bf16x4*)&VtB[((kh * 4 + quad) * 256 + d) * 4];
        o[tl] = MFMA16(ap, bv, o[tl]);
      }
#else
      bf16x8 ap8;
      if (quad < 2) ap8 = *(const bf16x8*)&PsW[l16 * PSTR + quad * 8];
      else          ap8 = bf16x8{0, 0, 0, 0, 0, 0, 0, 0};
      const int c4a = kh * 4 + (quad & 1) * 2;
      #pragma unroll
      for (int tl = 0; tl < 16; tl++) {
        const int d = tl * 16 + l16;
        union { bf16x8 v8; bf16x4 v4[2]; } bvu;
        bvu.v4[0] = *(const bf16x4*)&VtB[(c4a * 256 + d) * 4];
        bvu.v4[1] = *(const bf16x4*)&VtB[((c4a + 1) * 256 + d) * 4];
        o[tl] = __builtin_amdgcn_mfma_f32_16x16x32_bf16(ap8, bvu.v8, o[tl], 0, 0, 0);
      }
#endif
    }
    __syncthreads();  // buffer reuse gate + drains this iter's prefetch
  }

  // ---- epilogue: wave-local l reduce, cross-kh O/l sum via dead LDS ----
  float lr[4];
  #pragma unroll
  for (int r = 0; r < 4; r++) {
    float l = l_r[r];
    #pragma unroll
    for (int off = 1; off < 16; off <<= 1) l += __shfl_xor(l, off);
    lr[r] = l;
  }
  if (kh == 1) {
    f32x4* ob = (f32x4*)lds;   // 4 qs x 16 t x 64 lanes x 16B = 64KB (buffers, dead)
    #pragma unroll
    for (int t = 0; t < 16; t++) ob[(qs * 16 + t) * 64 + lane] = o[t];
    if (l16 == 0) {
      #pragma unroll
      for (int r = 0; r < 4; r++) lsumX[qs][quad * 4 + r] = lr[r];
    }
  }
  __syncthreads();
  if (kh == 0) {
    const f32x4* ob = (const f32x4*)lds;
    #pragma unroll
    for (int t = 0; t < 16; t++) o[t] += ob[(qs * 16 + t) * 64 + lane];
    float inv[4];
    #pragma unroll
    for (int r = 0; r < 4; r++) inv[r] = 1.0f / (lr[r] + lsumX[qs][quad * 4 + r]);
    #pragma unroll
    for (int r = 0; r < 4; r++) {
      int s = q0 + qs * 16 + quad * 4 + r;
      unsigned short* dst = oflat + (size_t)(b * SQL + h * 128 + (s >> 3)) * 2048 + (s & 7) * 256;
      #pragma unroll
      for (int t = 0; t < 16; t++)
        dst[t * 16 + l16] = f2bf(o[t][r] * inv[r]);
    }
  }
}

extern "C" void kernel_launch(void* const* d_in, const int* in_sizes, int n_in,
                              void* d_out, int out_size, void* d_ws, size_t ws_size,
                              hipStream_t stream) {
  const float* x      = (const float*)d_in[0];
  const float* w_attn = (const float*)d_in[1];
  const float* b_attn = (const float*)d_in[2];
  const float* w_out  = (const float*)d_in[3];
  const float* b_out  = (const float*)d_in[4];
  float* out = (float*)d_out;

  char* p = (char*)d_ws;
  unsigned short* proj = (unsigned short*)p;  p += (size_t)MROWS * NKV * 2;
  unsigned short* obf  = (unsigned short*)p;  p += (size_t)MROWS * 2048 * 2;
  unsigned short* vtb  = (unsigned short*)p;  p += (size_t)32 * EDIM * SQL * 2;
  unsigned short* xb   = (unsigned short*)p;  p += (size_t)MROWS * EDIM * 2;
  unsigned short* wb   = (unsigned short*)p;  p += (size_t)NKV * EDIM * 2;
  unsigned short* wob  = (unsigned short*)p;

  const int n0 = MROWS * EDIM / 8;        // 131072 -> 512 blocks
  const int n1 = NKV * EDIM / 8;          // 196608 -> 768 blocks
  const int n2 = EDIM * 2048 / 8;         // 65536  -> 256 blocks
  cast3_bf16<<<(n0 + n1 + n2) / 256, 256, 0, stream>>>(x, xb, n0, w_attn, wb, n1,
                                                       w_out, wob, n2);

  gemm_mfma<128, 128, unsigned short><<<dim3(MROWS / 128, NKV / 128), 256, 0, stream>>>(
      xb, wb, b_attn, proj, MROWS, NKV, EDIM);
  transpose_v<<<dim3(SQL / 64, EDIM / 64, 32), 256, 0, stream>>>(proj, vtb);
  attn_mfma<<<512, 512, 0, stream>>>(proj, vtb, obf);
  gemm_mfma<64, 64, float><<<dim3(MROWS / 64, EDIM / 64), 256, 0, stream>>>(
      obf, wob, b_out, out, MROWS, EDIM, NHD * EDIM);
}

// Round 7
// 186.077 us; speedup vs baseline: 1.1102x; 1.1102x over previous
//
#include <hip/hip_runtime.h>

#define SQL  1024
#define EDIM 256
#define NHD  8
#define NKV  (NHD * 3 * EDIM)   // 6144
#define MROWS (4 * SQL)         // 4096

typedef short bf16x8 __attribute__((ext_vector_type(8)));
typedef short bf16x4 __attribute__((ext_vector_type(4)));
typedef float f32x4 __attribute__((ext_vector_type(4)));

// ---- 16x16x16 bf16 MFMA builtin resolution (guarded; fallback = zero-padded 16x16x32)
#if defined(__has_builtin)
#if __has_builtin(__builtin_amdgcn_mfma_f32_16x16x16bf16_1k)
#define MFMA16(a, b, c) __builtin_amdgcn_mfma_f32_16x16x16bf16_1k(a, b, c, 0, 0, 0)
#define HAVE_MFMA16 1
#elif __has_builtin(__builtin_amdgcn_mfma_f32_16x16x16_bf16)
#define MFMA16(a, b, c) __builtin_amdgcn_mfma_f32_16x16x16_bf16(a, b, c, 0, 0, 0)
#define HAVE_MFMA16 1
#else
#define HAVE_MFMA16 0
#endif
#else
#define HAVE_MFMA16 0
#endif

// Ps row stride (shorts): 20 (=40B, b64-aligned, bank-optimal) for the
// 16x16x16 path; 24 (=48B, 16B-aligned) for the b128 fallback path.
constexpr int PSTR = HAVE_MFMA16 ? 20 : 24;

__device__ __forceinline__ unsigned short f2bf(float f) {
  unsigned u = __float_as_uint(f);
  u += 0x7fff + ((u >> 16) & 1);   // round-to-nearest-even (finite values)
  return (unsigned short)(u >> 16);
}

// async 16B global->LDS (direct-to-shared DMA; LDS dest must be
// wave-uniform base + lane*16 — all call sites use flat (it*T+tid)*16B)
__device__ __forceinline__ void g2lds16(const void* g, void* l) {
  __builtin_amdgcn_global_load_lds(
      (const __attribute__((address_space(1))) unsigned int*)g,
      (__attribute__((address_space(3))) unsigned int*)l, 16, 0, 0);
}

__device__ __forceinline__ void storev(float* p, float v) { *p = v; }
__device__ __forceinline__ void storev(unsigned short* p, float v) { *p = f2bf(v); }

// =====================================================================
// fused fp32 -> bf16 cast for all three inputs, 8 elems/thread.
// =====================================================================
__global__ __launch_bounds__(256) void cast3_bf16(
    const float* __restrict__ s0, unsigned short* __restrict__ d0, int n0,
    const float* __restrict__ s1, unsigned short* __restrict__ d1, int n1,
    const float* __restrict__ s2, unsigned short* __restrict__ d2, int n2) {
  int i = blockIdx.x * 256 + threadIdx.x;
  const float* s; unsigned short* d;
  if (i < n0) { s = s0; d = d0; }
  else if (i < n0 + n1) { i -= n0; s = s1; d = d1; }
  else { i -= n0 + n1; if (i >= n2) return; s = s2; d = d2; }
  float4 a = ((const float4*)s)[2 * i];
  float4 b = ((const float4*)s)[2 * i + 1];
  union { unsigned short u[8]; ulonglong2 v; } t;
  t.u[0] = f2bf(a.x); t.u[1] = f2bf(a.y); t.u[2] = f2bf(a.z); t.u[3] = f2bf(a.w);
  t.u[4] = f2bf(b.x); t.u[5] = f2bf(b.y); t.u[6] = f2bf(b.z); t.u[7] = f2bf(b.w);
  ((ulonglong2*)d)[i] = t.v;
}

// =====================================================================
// bf16 MFMA NT-GEMM, double-buffered global_load_lds staging.
// (round-0 proven version)
// =====================================================================
template <int BM, int BN, typename OutT>
__global__ __launch_bounds__(256) void gemm_mfma(
    const unsigned short* __restrict__ A, const unsigned short* __restrict__ B,
    const float* __restrict__ bias, OutT* __restrict__ C,
    int M, int N, int K) {
  constexpr int TM = BM / 32, TN = BN / 32;
  __shared__ __align__(16) unsigned short As[2][BM * 32];
  __shared__ __align__(16) unsigned short Bs[2][BN * 32];
  const int tid = threadIdx.x;
  const int wave = tid >> 6, lane = tid & 63;
  const int quad = lane >> 4, l16 = lane & 15;
  const int wm = (wave >> 1) * (BM / 2), wn = (wave & 1) * (BN / 2);
  const int m0 = blockIdx.x * BM, n0 = blockIdx.y * BN;
  const int sw = (l16 >> 1) & 3;

  f32x4 acc[TM][TN];
  #pragma unroll
  for (int i = 0; i < TM; i++)
    #pragma unroll
    for (int j = 0; j < TN; j++) acc[i][j] = {0.f, 0.f, 0.f, 0.f};

  auto stage = [&](int k0, int bb) {
    #pragma unroll
    for (int it = 0; it < BM / 64; it++) {
      int flat = it * 256 + tid;
      int row = flat >> 2;
      int cg = (flat & 3) ^ ((row >> 1) & 3);
      g2lds16(A + (size_t)(m0 + row) * K + k0 + cg * 8, &As[bb][flat * 8]);
    }
    #pragma unroll
    for (int it = 0; it < BN / 64; it++) {
      int flat = it * 256 + tid;
      int row = flat >> 2;
      int cg = (flat & 3) ^ ((row >> 1) & 3);
      g2lds16(B + (size_t)(n0 + row) * K + k0 + cg * 8, &Bs[bb][flat * 8]);
    }
  };

  stage(0, 0);
  __syncthreads();
  for (int k0 = 0; k0 < K; k0 += 32) {
    const int bb = (k0 >> 5) & 1;
    if (k0 + 32 < K) stage(k0 + 32, bb ^ 1);
    bf16x8 af[TM], bf[TN];
    #pragma unroll
    for (int i = 0; i < TM; i++)
      af[i] = *(const bf16x8*)&As[bb][(wm + i * 16 + l16) * 32 + (quad ^ sw) * 8];
    #pragma unroll
    for (int j = 0; j < TN; j++)
      bf[j] = *(const bf16x8*)&Bs[bb][(wn + j * 16 + l16) * 32 + (quad ^ sw) * 8];
    #pragma unroll
    for (int i = 0; i < TM; i++)
      #pragma unroll
      for (int j = 0; j < TN; j++)
        acc[i][j] = __builtin_amdgcn_mfma_f32_16x16x32_bf16(af[i], bf[j], acc[i][j], 0, 0, 0);
    __syncthreads();  // gates buffer reuse + drains this iter's prefetch
  }

  #pragma unroll
  for (int i = 0; i < TM; i++) {
    #pragma unroll
    for (int r = 0; r < 4; r++) {
      int m = m0 + wm + i * 16 + quad * 4 + r;
      #pragma unroll
      for (int j = 0; j < TN; j++) {
        int n = n0 + wn + j * 16 + l16;
        storev(&C[(size_t)m * N + n], acc[i][j][r] + bias[n]);
      }
    }
  }
}

// =====================================================================
// V transpose -> kt-tile-major, k-chunk4-major layout:
// vt[bh][kt][c4][d][i]  (short index = (((bh*32+kt)*8 + c4)*256 + d)*4 + i)
// where element = V[key = kt*32 + c4*4 + i][d]. Staging a kt tile into
// LDS is a flat 16KB copy; the PV b64 read VtB[(c4*256+d)*4] has each
// 16-lane quad-group covering all 32 banks (floor-optimal, no swizzle
// needed). Writes here stay coalesced: 64 consecutive lanes write 64
// consecutive 8B chunks (512B runs).
// =====================================================================
__global__ __launch_bounds__(256) void transpose_v(
    const unsigned short* __restrict__ proj, unsigned short* __restrict__ vt) {
  __shared__ unsigned short T[64][66];
  const int tid = threadIdx.x;
  const int s0 = blockIdx.x * 64, d0 = blockIdx.y * 64, bh = blockIdx.z;
  const int b = bh >> 3, h = bh & 7;
  #pragma unroll
  for (int it = 0; it < 2; it++) {
    int c = it * 256 + tid;
    int sr = c >> 3, d8 = (c & 7) * 8;
    int s = s0 + sr;
    const unsigned short* src = proj + (size_t)(b * SQL + h * 128 + (s >> 3)) * NKV
                                + 2 * 2048 + (s & 7) * 256 + d0 + d8;
    *(ulonglong2*)&T[sr][d8] = *(const ulonglong2*)src;
  }
  __syncthreads();
  #pragma unroll
  for (int it = 0; it < 2; it++) {
    int c = it * 256 + tid;
    int dr = c & 63, sg = c >> 6;          // sg in 0..7 (8 keys each)
    unsigned short tmp[8];
    #pragma unroll
    for (int j = 0; j < 8; j++) tmp[j] = T[sg * 8 + j][dr];
    const int d = d0 + dr;
    const int t = (s0 >> 5) + (sg >> 2);   // kt tile index
    const int c4 = (sg & 3) * 2;           // first k-chunk4 of this 8-key group
    unsigned short* base = vt + (((size_t)(bh * 32 + t) * 8 + c4) * 256 + d) * 4;
    uint2 w0, w1;
    w0.x = (unsigned)tmp[0] | ((unsigned)tmp[1] << 16);
    w0.y = (unsigned)tmp[2] | ((unsigned)tmp[3] << 16);
    w1.x = (unsigned)tmp[4] | ((unsigned)tmp[5] << 16);
    w1.y = (unsigned)tmp[6] | ((unsigned)tmp[7] << 16);
    *(uint2*)base          = w0;           // chunk c4
    *(uint2*)(base + 1024) = w1;           // chunk c4+1 (+256*4 shorts)
  }
}

// =====================================================================
// bf16 MFMA flash attention, round 9: R6 structure + VGPR-cap fix.
// R6's ONLY failure was __launch_bounds__(512,4): hipcc capped VGPRs
// at 64 (R3/R6 evidence: (512,4)->64, (512,2)->cap 128) while the
// kernel needs ~115 (o[16]=64 + aq[8]=32 + temps) -> scratch spill:
// WRITE_SIZE 16.4->39.9MB, FETCH +12MB, dur 85us with all pipes idle.
// Fix: __launch_bounds__(512,2) = 128-VGPR cap. LDS 71KB still admits
// 2 blocks/CU -> 4 waves/SIMD (the R6-validated occupancy).
// Structure (validated correct by R6): 8 waves (qs 0..3, kh 0..1),
// each = HALF an R0 wave: QK over a private 16-key half (8 MFMA, no
// duplication), private half-softmax, private Ps slice, PV over the
// key-half via 16x16x16 MFMA; cross-kh O/l sum in epilogue via dead
// buffer LDS. One barrier per kt, full wave independence between
// barriers, kt=32 dbuf staging.
// =====================================================================
__global__ __launch_bounds__(512, 2) void attn_mfma(
    const unsigned short* __restrict__ proj,
    const unsigned short* __restrict__ vt,
    unsigned short* __restrict__ oflat) {
  // shorts: buf0 @0 (K 8192 | V 8192) | buf1 @16384 | Ps @32768 (8 x 16 x PSTR)
  __shared__ __align__(16) unsigned short lds[32768 + 8 * 16 * PSTR];
  __shared__ float lsumX[4][16];
  unsigned short* Ps = lds + 32768;

  const int tid = threadIdx.x;          // 0..511
  const int wave = tid >> 6, lane = tid & 63;
  const int quad = lane >> 4, l16 = lane & 15;
  const int qs = wave >> 1;             // q-row subtile: rows qs*16..+15
  const int kh = wave & 1;              // key half within each kt tile
  // balanced decode: slot s -> (bh = s&31, j = s>>5); round 0 heavy, 1 light
  const int slot = blockIdx.x & 255, round = blockIdx.x >> 8;
  const int bh = slot & 31;
  const int jj = slot >> 5;
  const int qt = round ? jj : 15 - jj;
  const int b = bh >> 3, h = bh & 7;
  const int q0 = qt * 64;

  auto stage = [&](int kt, int bb) {
    unsigned short* B = lds + bb * 16384;
    #pragma unroll
    for (int it = 0; it < 2; it++) {   // K tile 32 x 256 (16KB), swizzled
      int c = it * 512 + tid;
      int r = c >> 5, ch = (c & 31) ^ (r & 7);
      int s = kt * 32 + r;
      g2lds16(proj + (size_t)(b * SQL + h * 128 + (s >> 3)) * NKV + 2048 + (s & 7) * 256 + ch * 8,
              B + c * 8);
    }
    const unsigned short* vsrc = vt + ((size_t)bh * 32 + kt) * 8192;
    #pragma unroll
    for (int it = 0; it < 2; it++) {   // V tile: flat 16KB copy (tile-major layout)
      int c = it * 512 + tid;
      g2lds16(vsrc + c * 8, B + 8192 + c * 8);
    }
  };

  // ---- prologue: kt0 -> buf0, Q (64x256, 32KB) -> buf1 region ----
  stage(0, 0);
  #pragma unroll
  for (int it = 0; it < 4; it++) {
    int c = it * 512 + tid;
    int r = c >> 5, ch = (c & 31) ^ (r & 7);
    int s = q0 + r;
    g2lds16(proj + (size_t)(b * SQL + h * 128 + (s >> 3)) * NKV + (s & 7) * 256 + ch * 8,
            lds + 16384 + c * 8);
  }
  __syncthreads();
  bf16x8 aq[8];
  const int qrow = qs * 16 + l16;
  #pragma unroll
  for (int kk = 0; kk < 8; kk++)
    aq[kk] = *(const bf16x8*)&lds[16384 + qrow * 256 + ((kk * 4 + quad) ^ (qrow & 7)) * 8];
  __syncthreads();  // all waves done reading Q before buf1 overwrite

  f32x4 o[16];
  #pragma unroll
  for (int t = 0; t < 16; t++) o[t] = {0.f, 0.f, 0.f, 0.f};
  float l_r[4] = {0.f, 0.f, 0.f, 0.f};

  const int nkt = 2 * qt + 2;
  for (int kt = 0; kt < nkt; kt++) {
    const int bb = kt & 1;
    if (kt + 1 < nkt) stage(kt + 1, bb ^ 1);  // prefetch into other buffer
    const unsigned short* KsB = lds + bb * 16384;
    const unsigned short* VtB = KsB + 8192;
    // wave's 16 keys: kt*32 + kh*16 .. +15; skip if fully masked
    const bool live = (kt * 32 + kh * 16 <= q0 + qs * 16 + 15);

    if (live) {
      // ---- S = Q K^T : 16 q-rows x my 16-key half (8 MFMA) ----
      f32x4 s0 = {0.f, 0.f, 0.f, 0.f};
      const int krow = kh * 16 + l16;
      #pragma unroll
      for (int kk = 0; kk < 8; kk++) {
        bf16x8 bk = *(const bf16x8*)&KsB[krow * 256 + ((kk * 4 + quad) ^ (l16 & 7)) * 8];
        s0 = __builtin_amdgcn_mfma_f32_16x16x32_bf16(aq[kk], bk, s0, 0, 0, 0);
      }

      // ---- half-softmax: p = exp2(s/16*log2e), lane-local l ----
      const int kg = kt * 32 + kh * 16 + l16;
      unsigned short* PsW = Ps + wave * 16 * PSTR;  // private [16][PSTR]
      #pragma unroll
      for (int r = 0; r < 4; r++) {
        int qg = q0 + qs * 16 + quad * 4 + r;
        float p0 = (kg <= qg) ? exp2f(s0[r] * 0.09016844f) : 0.f;
        l_r[r] += p0;
        PsW[(quad * 4 + r) * PSTR + l16] = f2bf(p0);
      }

      // ---- PV over my 16-key half, full d=256 ----
#if HAVE_MFMA16
      bf16x4 ap = *(const bf16x4*)&PsW[l16 * PSTR + quad * 4];
      #pragma unroll
      for (int tl = 0; tl < 16; tl++) {
        const int d = tl * 16 + l16;
        bf16x4 bv = *(const bf16x4*)&VtB[((kh * 4 + quad) * 256 + d) * 4];
        o[tl] = MFMA16(ap, bv, o[tl]);
      }
#else
      bf16x8 ap8;
      if (quad < 2) ap8 = *(const bf16x8*)&PsW[l16 * PSTR + quad * 8];
      else          ap8 = bf16x8{0, 0, 0, 0, 0, 0, 0, 0};
      const int c4a = kh * 4 + (quad & 1) * 2;
      #pragma unroll
      for (int tl = 0; tl < 16; tl++) {
        const int d = tl * 16 + l16;
        union { bf16x8 v8; bf16x4 v4[2]; } bvu;
        bvu.v4[0] = *(const bf16x4*)&VtB[(c4a * 256 + d) * 4];
        bvu.v4[1] = *(const bf16x4*)&VtB[((c4a + 1) * 256 + d) * 4];
        o[tl] = __builtin_amdgcn_mfma_f32_16x16x32_bf16(ap8, bvu.v8, o[tl], 0, 0, 0);
      }
#endif
    }
    __syncthreads();  // buffer reuse gate + drains this iter's prefetch
  }

  // ---- epilogue: wave-local l reduce, cross-kh O/l sum via dead LDS ----
  float lr[4];
  #pragma unroll
  for (int r = 0; r < 4; r++) {
    float l = l_r[r];
    #pragma unroll
    for (int off = 1; off < 16; off <<= 1) l += __shfl_xor(l, off);
    lr[r] = l;
  }
  if (kh == 1) {
    f32x4* ob = (f32x4*)lds;   // 4 qs x 16 t x 64 lanes x 16B = 64KB (buffers, dead)
    #pragma unroll
    for (int t = 0; t < 16; t++) ob[(qs * 16 + t) * 64 + lane] = o[t];
    if (l16 == 0) {
      #pragma unroll
      for (int r = 0; r < 4; r++) lsumX[qs][quad * 4 + r] = lr[r];
    }
  }
  __syncthreads();
  if (kh == 0) {
    const f32x4* ob = (const f32x4*)lds;
    #pragma unroll
    for (int t = 0; t < 16; t++) o[t] += ob[(qs * 16 + t) * 64 + lane];
    float inv[4];
    #pragma unroll
    for (int r = 0; r < 4; r++) inv[r] = 1.0f / (lr[r] + lsumX[qs][quad * 4 + r]);
    #pragma unroll
    for (int r = 0; r < 4; r++) {
      int s = q0 + qs * 16 + quad * 4 + r;
      unsigned short* dst = oflat + (size_t)(b * SQL + h * 128 + (s >> 3)) * 2048 + (s & 7) * 256;
      #pragma unroll
      for (int t = 0; t < 16; t++)
        dst[t * 16 + l16] = f2bf(o[t][r] * inv[r]);
    }
  }
}

extern "C" void kernel_launch(void* const* d_in, const int* in_sizes, int n_in,
                              void* d_out, int out_size, void* d_ws, size_t ws_size,
                              hipStream_t stream) {
  const float* x      = (const float*)d_in[0];
  const float* w_attn = (const float*)d_in[1];
  const float* b_attn = (const float*)d_in[2];
  const float* w_out  = (const float*)d_in[3];
  const float* b_out  = (const float*)d_in[4];
  float* out = (float*)d_out;

  char* p = (char*)d_ws;
  unsigned short* proj = (unsigned short*)p;  p += (size_t)MROWS * NKV * 2;
  unsigned short* obf  = (unsigned short*)p;  p += (size_t)MROWS * 2048 * 2;
  unsigned short* vtb  = (unsigned short*)p;  p += (size_t)32 * EDIM * SQL * 2;
  unsigned short* xb   = (unsigned short*)p;  p += (size_t)MROWS * EDIM * 2;
  unsigned short* wb   = (unsigned short*)p;  p += (size_t)NKV * EDIM * 2;
  unsigned short* wob  = (unsigned short*)p;

  const int n0 = MROWS * EDIM / 8;        // 131072 -> 512 blocks
  const int n1 = NKV * EDIM / 8;          // 196608 -> 768 blocks
  const int n2 = EDIM * 2048 / 8;         // 65536  -> 256 blocks
  cast3_bf16<<<(n0 + n1 + n2) / 256, 256, 0, stream>>>(x, xb, n0, w_attn, wb, n1,
                                                       w_out, wob, n2);

  gemm_mfma<128, 128, unsigned short><<<dim3(MROWS / 128, NKV / 128), 256, 0, stream>>>(
      xb, wb, b_attn, proj, MROWS, NKV, EDIM);
  transpose_v<<<dim3(SQL / 64, EDIM / 64, 32), 256, 0, stream>>>(proj, vtb);
  attn_mfma<<<512, 512, 0, stream>>>(proj, vtb, obf);
  gemm_mfma<64, 64, float><<<dim3(MROWS / 64, EDIM / 64), 256, 0, stream>>>(
      obf, wob, b_out, out, MROWS, EDIM, NHD * EDIM);
}